// Round 1
// baseline (1727.448 us; speedup 1.0000x reference)
//
#include <hip/hip_runtime.h>
#include <hip/hip_bf16.h>

#define NNODES 4096
#define NBATCH 4096
#define NBLK 8
#define LN_EPS 1e-5f

typedef __attribute__((ext_vector_type(8))) short short8;
typedef __attribute__((ext_vector_type(4))) float f32x4;
typedef __attribute__((ext_vector_type(4))) unsigned short u16x4;
typedef unsigned short u16;

__device__ __forceinline__ u16 bf16_rn(float f) {
  unsigned int u = __builtin_bit_cast(unsigned int, f);
  u += 0x7fffu + ((u >> 16) & 1u);
  return (u16)(u >> 16);
}

__device__ __forceinline__ void load_lds16(const void* g, void* l) {
  __builtin_amdgcn_global_load_lds((const __attribute__((address_space(1))) void*)g,
                                   (__attribute__((address_space(3))) void*)l,
                                   16, 0, 0);
}

// ---- W f32 -> bf16 convert: one layer (4096x4096), 4 elems/thread ----
__global__ __launch_bounds__(256) void convw_kernel(const float* __restrict__ W,
                                                    u16* __restrict__ Wb) {
  int idx = blockIdx.x * 256 + threadIdx.x;  // float4 index
  float4 v = ((const float4*)W)[idx];
  u16x4 o;
  o[0] = bf16_rn(v.x); o[1] = bf16_rn(v.y); o[2] = bf16_rn(v.z); o[3] = bf16_rn(v.w);
  ((u16x4*)Wb)[idx] = o;
}

// ---- row LayerNorm: f32 in -> bf16 out, one block (256 thr) per row ----
__global__ __launch_bounds__(256) void ln_kernel(const float* __restrict__ x,
                                                 const float* __restrict__ g,
                                                 const float* __restrict__ bt,
                                                 u16* __restrict__ out) {
  int row = blockIdx.x;
  int t = threadIdx.x;
  const float4* xr = (const float4*)(x + (size_t)row * NNODES);
  float4 v[4];
  float s = 0.f, ss = 0.f;
#pragma unroll
  for (int q = 0; q < 4; ++q) {
    v[q] = xr[q * 256 + t];
    s  += v[q].x + v[q].y + v[q].z + v[q].w;
    ss += v[q].x * v[q].x + v[q].y * v[q].y + v[q].z * v[q].z + v[q].w * v[q].w;
  }
#pragma unroll
  for (int off = 32; off >= 1; off >>= 1) {
    s  += __shfl_xor(s, off, 64);
    ss += __shfl_xor(ss, off, 64);
  }
  __shared__ float sh[8];
  int wid = t >> 6, lane = t & 63;
  if (lane == 0) { sh[wid] = s; sh[wid + 4] = ss; }
  __syncthreads();
  s  = sh[0] + sh[1] + sh[2] + sh[3];
  ss = sh[4] + sh[5] + sh[6] + sh[7];
  float mu  = s * (1.f / NNODES);
  float var = ss * (1.f / NNODES) - mu * mu;
  float rs  = rsqrtf(var + LN_EPS);
  u16x4* o = (u16x4*)(out + (size_t)row * NNODES);
  const float4* gv = (const float4*)g;
  const float4* bv = (const float4*)bt;
#pragma unroll
  for (int q = 0; q < 4; ++q) {
    int i = q * 256 + t;
    float4 gg = gv[i], bb = bv[i];
    u16x4 ov;
    ov[0] = bf16_rn((v[q].x - mu) * rs * gg.x + bb.x);
    ov[1] = bf16_rn((v[q].y - mu) * rs * gg.y + bb.y);
    ov[2] = bf16_rn((v[q].z - mu) * rs * gg.z + bb.z);
    ov[3] = bf16_rn((v[q].w - mu) * rs * gg.w + bb.w);
    o[i] = ov;
  }
}

// ---- bf16 NT GEMM 128x128 tile, BK=64, m97 structure ----
// C[b][m] = sum_k A[b][k] * B[m][k] + bias[m], then per-feature LeakyReLU
__global__ __launch_bounds__(256) void gemm_kernel(const u16* __restrict__ A,
                                                   const u16* __restrict__ B,
                                                   const float* __restrict__ bias,
                                                   const float* __restrict__ slope,
                                                   float* __restrict__ C) {
  constexpr int K = NNODES, LDC = NNODES, BK = 64;
  __shared__ u16 Alds[128 * BK];
  __shared__ u16 Blds[128 * BK];
  int tid = threadIdx.x;
  int brow = blockIdx.y * 128;
  int bcol = blockIdx.x * 128;
  int wid = tid >> 6, lane = tid & 63;
  int wr = wid >> 1, wc = wid & 1;

  f32x4 acc[4][4] = {};

  // staging addressing: thread t -> row t/8 (of 32), 8 bf16 at col (t%8)*8
  int srow = tid >> 3;
  int scol = (tid & 7) * 8;
  const u16* Ag = A + (size_t)(brow + srow) * K + scol;
  const u16* Bg = B + (size_t)(bcol + srow) * K + scol;
  u16* Al = Alds + tid * 8;   // byte offset tid*16: wave-uniform base + lane*16
  u16* Bl = Blds + tid * 8;

  int r16 = lane & 15, kq = lane >> 4;
  const u16* Ard = Alds + (wr * 64 + r16) * BK + kq * 8;
  const u16* Brd = Blds + (wc * 64 + r16) * BK + kq * 8;

  for (int k0 = 0; k0 < K; k0 += BK) {
#pragma unroll
    for (int q = 0; q < 4; ++q) {
      load_lds16(Ag + (size_t)(q * 32) * K + k0, Al + q * 2048);
      load_lds16(Bg + (size_t)(q * 32) * K + k0, Bl + q * 2048);
    }
    __syncthreads();   // drains vmcnt+lgkm, then barrier

    short8 a[2][4], b[2][4];
#pragma unroll
    for (int kk = 0; kk < 2; ++kk)
#pragma unroll
      for (int m = 0; m < 4; ++m) {
        a[kk][m] = *(const short8*)(Ard + m * 16 * BK + kk * 32);
        b[kk][m] = *(const short8*)(Brd + m * 16 * BK + kk * 32);
      }
#pragma unroll
    for (int kk = 0; kk < 2; ++kk)
#pragma unroll
      for (int m = 0; m < 4; ++m)
#pragma unroll
        for (int n = 0; n < 4; ++n)
          acc[m][n] = __builtin_amdgcn_mfma_f32_16x16x32_bf16(a[kk][m], b[kk][n],
                                                              acc[m][n], 0, 0, 0);
    __syncthreads();   // protect LDS before next stage
  }

  // epilogue: bias + per-feature LeakyReLU, f32 store
  int colbase = bcol + wc * 64;
  int rowbase = brow + wr * 64;
#pragma unroll
  for (int n = 0; n < 4; ++n) {
    int col = colbase + n * 16 + (lane & 15);
    float bv = bias[col], sv = slope[col];
#pragma unroll
    for (int m = 0; m < 4; ++m) {
      int row0 = rowbase + m * 16 + (lane >> 4) * 4;
#pragma unroll
      for (int r = 0; r < 4; ++r) {
        float vv = acc[m][n][r] + bv;
        vv = vv < 0.f ? vv * sv : vv;
        C[(size_t)(row0 + r) * LDC + col] = vv;
      }
    }
  }
}

extern "C" void kernel_launch(void* const* d_in, const int* in_sizes, int n_in,
                              void* d_out, int out_size, void* d_ws, size_t ws_size,
                              hipStream_t stream) {
  const float* x     = (const float*)d_in[0];
  const float* ln_g  = (const float*)d_in[1];
  const float* ln_b  = (const float*)d_in[2];
  const float* W     = (const float*)d_in[3];
  const float* b     = (const float*)d_in[4];
  const float* slope = (const float*)d_in[5];
  float* out = (float*)d_out;

  char* ws = (char*)d_ws;
  u16*   Wbuf  = (u16*)ws;                                   // 32 MB
  u16*   lnbuf = (u16*)(ws + (size_t)32 * 1024 * 1024);      // 32 MB
  float* ybuf  = (float*)(ws + (size_t)64 * 1024 * 1024);    // 64 MB

  const size_t WN = (size_t)NNODES * NNODES;

  for (int i = 0; i < NBLK; ++i) {
    // even layers write ybuf, odd layers write d_out; layer 7 (odd) -> d_out
    const float* xin = (i == 0) ? x : ((i & 1) ? ybuf : out);
    float* ydst = (i & 1) ? out : ybuf;

    convw_kernel<<<dim3(WN / 4 / 256), dim3(256), 0, stream>>>(W + WN * i, Wbuf);
    ln_kernel<<<dim3(NBATCH), dim3(256), 0, stream>>>(xin, ln_g + (size_t)i * NNODES,
                                                      ln_b + (size_t)i * NNODES, lnbuf);
    gemm_kernel<<<dim3(32, 32), dim3(256), 0, stream>>>(lnbuf, Wbuf,
                                                        b + (size_t)i * NNODES,
                                                        slope + (size_t)i * NNODES, ydst);
  }
}

// Round 2
// 1315.289 us; speedup vs baseline: 1.3134x; 1.3134x over previous
//
#include <hip/hip_runtime.h>
#include <hip/hip_bf16.h>

#define NNODES 4096
#define NBATCH 4096
#define NBLK 8
#define LN_EPS 1e-5f

typedef __attribute__((ext_vector_type(8))) short short8;
typedef __attribute__((ext_vector_type(4))) float f32x4;
typedef __attribute__((ext_vector_type(4))) unsigned short u16x4;
typedef unsigned short u16;

__device__ __forceinline__ u16 bf16_rn(float f) {
  unsigned int u = __builtin_bit_cast(unsigned int, f);
  u += 0x7fffu + ((u >> 16) & 1u);
  return (u16)(u >> 16);
}

__device__ __forceinline__ void load_lds16(const void* g, void* l) {
  __builtin_amdgcn_global_load_lds((const __attribute__((address_space(1))) void*)g,
                                   (__attribute__((address_space(3))) void*)l,
                                   16, 0, 0);
}

// stage one 256x32 bf16 subtile: 2 x (512 thr x 16B) = 16KB
__device__ __forceinline__ void stage_sub(const u16* g, u16* l) {
  load_lds16(g, l);                                   // rows 0..127
  load_lds16(g + (size_t)128 * NNODES, l + 4096);     // rows 128..255
}

// ---- W f32 -> bf16 convert ----
__global__ __launch_bounds__(256) void convw_kernel(const float* __restrict__ W,
                                                    u16* __restrict__ Wb) {
  int idx = blockIdx.x * 256 + threadIdx.x;
  float4 v = ((const float4*)W)[idx];
  u16x4 o;
  o[0] = bf16_rn(v.x); o[1] = bf16_rn(v.y); o[2] = bf16_rn(v.z); o[3] = bf16_rn(v.w);
  ((u16x4*)Wb)[idx] = o;
}

// ---- row LayerNorm: f32 in -> bf16 out ----
__global__ __launch_bounds__(256) void ln_kernel(const float* __restrict__ x,
                                                 const float* __restrict__ g,
                                                 const float* __restrict__ bt,
                                                 u16* __restrict__ out) {
  int row = blockIdx.x;
  int t = threadIdx.x;
  const float4* xr = (const float4*)(x + (size_t)row * NNODES);
  float4 v[4];
  float s = 0.f, ss = 0.f;
#pragma unroll
  for (int q = 0; q < 4; ++q) {
    v[q] = xr[q * 256 + t];
    s  += v[q].x + v[q].y + v[q].z + v[q].w;
    ss += v[q].x * v[q].x + v[q].y * v[q].y + v[q].z * v[q].z + v[q].w * v[q].w;
  }
#pragma unroll
  for (int off = 32; off >= 1; off >>= 1) {
    s  += __shfl_xor(s, off, 64);
    ss += __shfl_xor(ss, off, 64);
  }
  __shared__ float sh[8];
  int wid = t >> 6, lane = t & 63;
  if (lane == 0) { sh[wid] = s; sh[wid + 4] = ss; }
  __syncthreads();
  s  = sh[0] + sh[1] + sh[2] + sh[3];
  ss = sh[4] + sh[5] + sh[6] + sh[7];
  float mu  = s * (1.f / NNODES);
  float var = ss * (1.f / NNODES) - mu * mu;
  float rs  = rsqrtf(var + LN_EPS);
  u16x4* o = (u16x4*)(out + (size_t)row * NNODES);
  const float4* gv = (const float4*)g;
  const float4* bv = (const float4*)bt;
#pragma unroll
  for (int q = 0; q < 4; ++q) {
    int i = q * 256 + t;
    float4 gg = gv[i], bb = bv[i];
    u16x4 ov;
    ov[0] = bf16_rn((v[q].x - mu) * rs * gg.x + bb.x);
    ov[1] = bf16_rn((v[q].y - mu) * rs * gg.y + bb.y);
    ov[2] = bf16_rn((v[q].z - mu) * rs * gg.z + bb.z);
    ov[3] = bf16_rn((v[q].w - mu) * rs * gg.w + bb.w);
    o[i] = ov;
  }
}

// ---- 256x256 bf16 NT GEMM, 8 waves, 4-slot LDS ring of 256x32 subtiles ----
// C[b][m] = sum_k A[b][k]*B[m][k] + bias[m]; per-feature LeakyReLU.
__global__ __launch_bounds__(512, 2) void gemm256_kernel(const u16* __restrict__ A,
                                                         const u16* __restrict__ B,
                                                         const float* __restrict__ bias,
                                                         const float* __restrict__ slope,
                                                         float* __restrict__ C) {
  constexpr int Kdim = NNODES;
  constexpr int NSUB = Kdim / 32;   // 128 subtiles of K=32
  __shared__ u16 Alds[4][8192];     // 4 ring slots x 256x32 bf16 = 64KB
  __shared__ u16 Blds[4][8192];     // 64KB

  const int tid  = threadIdx.x;
  const int lane = tid & 63;
  const int wid  = tid >> 6;
  const int wr   = wid >> 2;        // 0..1 : row half (128 rows)
  const int wc   = wid & 3;         // 0..3 : col quarter (64 cols)

  // XCD-aware bijective swizzle (256 blocks, 8 XCDs)
  int bid = blockIdx.x;
  int swz = (bid & 7) * 32 + (bid >> 3);
  const int brow = (swz >> 4) * 256;
  const int bcol = (swz & 15) * 256;

  // staging: thread t -> row t/4 (+128 for 2nd instr), 16B chunk t&3, XOR-swizzled source
  const int srow = tid >> 2;
  const int scsw = (tid & 3) ^ ((srow >> 1) & 3);
  const u16* Ag = A + (size_t)(brow + srow) * Kdim + scsw * 8;
  const u16* Bg = B + (size_t)(bcol + srow) * Kdim + scsw * 8;

  // ds_read: lane -> row r16, k-chunk kq, swizzled chunk ck
  const int r16 = lane & 15, kq = lane >> 4;
  const int ck  = kq ^ ((r16 >> 1) & 3);
  const int aoff = (wr * 128 + r16) * 32 + ck * 8;  // + m*512 per frag
  const int boff = (wc * 64 + r16) * 32 + ck * 8;   // + n*512 per frag

  f32x4 acc[8][4] = {};

  // prologue: stage subtiles 0,1,2 (12 loads); certify subtile 0 cross-wave
#pragma unroll
  for (int s = 0; s < 3; ++s) {
    stage_sub(Ag + s * 32, &Alds[s][0] + tid * 8);
    stage_sub(Bg + s * 32, &Blds[s][0] + tid * 8);
  }
  asm volatile("s_waitcnt vmcnt(8)" ::: "memory");
  __builtin_amdgcn_s_barrier();

  for (int s = 0; s < NSUB; ++s) {
    const int sl = s & 3;
    const u16* abase = &Alds[sl][0] + aoff;
    const u16* bbase = &Blds[sl][0] + boff;
    short8 afr[4], bfr[4];

    // ---------- phase 0: B all + A m0-3, stage A(s+3) ----------
#pragma unroll
    for (int n = 0; n < 4; ++n) bfr[n] = *(const short8*)(bbase + n * 512);
#pragma unroll
    for (int m = 0; m < 4; ++m) afr[m] = *(const short8*)(abase + m * 512);
    if (s + 3 < NSUB) stage_sub(Ag + (s + 3) * 32, &Alds[(s + 3) & 3][0] + tid * 8);
    __builtin_amdgcn_s_barrier();
    asm volatile("s_waitcnt lgkmcnt(0)" ::: "memory");
    __builtin_amdgcn_sched_barrier(0);
    __builtin_amdgcn_s_setprio(1);
#pragma unroll
    for (int m = 0; m < 4; ++m)
#pragma unroll
      for (int n = 0; n < 4; ++n)
        acc[m][n] = __builtin_amdgcn_mfma_f32_16x16x32_bf16(afr[m], bfr[n], acc[m][n], 0, 0, 0);
    __builtin_amdgcn_s_setprio(0);
    __builtin_amdgcn_s_barrier();

    // ---------- phase 1: A m4-7, stage B(s+3), certify subtile s+1 ----------
#pragma unroll
    for (int m = 0; m < 4; ++m) afr[m] = *(const short8*)(abase + (m + 4) * 512);
    if (s + 3 < NSUB) stage_sub(Bg + (s + 3) * 32, &Blds[(s + 3) & 3][0] + tid * 8);
    // counted vmcnt BEFORE the barrier => cross-wave guarantee for slot (s+1)&3
    if (s <= NSUB - 4)      asm volatile("s_waitcnt vmcnt(8)" ::: "memory");
    else if (s == NSUB - 3) asm volatile("s_waitcnt vmcnt(4)" ::: "memory");
    else if (s == NSUB - 2) asm volatile("s_waitcnt vmcnt(0)" ::: "memory");
    __builtin_amdgcn_s_barrier();
    asm volatile("s_waitcnt lgkmcnt(0)" ::: "memory");
    __builtin_amdgcn_sched_barrier(0);
    __builtin_amdgcn_s_setprio(1);
#pragma unroll
    for (int m = 0; m < 4; ++m)
#pragma unroll
      for (int n = 0; n < 4; ++n)
        acc[m + 4][n] = __builtin_amdgcn_mfma_f32_16x16x32_bf16(afr[m], bfr[n], acc[m + 4][n], 0, 0, 0);
    __builtin_amdgcn_s_setprio(0);
    __builtin_amdgcn_s_barrier();
  }

  // epilogue: bias + per-feature LeakyReLU, f32 store
  const int crow0 = brow + wr * 128 + (lane >> 4) * 4;
  const int ccol0 = bcol + wc * 64 + r16;
#pragma unroll
  for (int n = 0; n < 4; ++n) {
    int col = ccol0 + n * 16;
    float bv = bias[col], sv = slope[col];
#pragma unroll
    for (int m = 0; m < 8; ++m) {
      int row0 = crow0 + m * 16;
#pragma unroll
      for (int r = 0; r < 4; ++r) {
        float vv = acc[m][n][r] + bv;
        vv = vv < 0.f ? vv * sv : vv;
        C[(size_t)(row0 + r) * NNODES + col] = vv;
      }
    }
  }
}

extern "C" void kernel_launch(void* const* d_in, const int* in_sizes, int n_in,
                              void* d_out, int out_size, void* d_ws, size_t ws_size,
                              hipStream_t stream) {
  const float* x     = (const float*)d_in[0];
  const float* ln_g  = (const float*)d_in[1];
  const float* ln_b  = (const float*)d_in[2];
  const float* W     = (const float*)d_in[3];
  const float* b     = (const float*)d_in[4];
  const float* slope = (const float*)d_in[5];
  float* out = (float*)d_out;

  char* ws = (char*)d_ws;
  u16*   Wbuf  = (u16*)ws;                                   // 32 MB
  u16*   lnbuf = (u16*)(ws + (size_t)32 * 1024 * 1024);      // 32 MB
  float* ybuf  = (float*)(ws + (size_t)64 * 1024 * 1024);    // 64 MB

  const size_t WN = (size_t)NNODES * NNODES;

  for (int i = 0; i < NBLK; ++i) {
    const float* xin = (i == 0) ? x : ((i & 1) ? ybuf : out);
    float* ydst = (i & 1) ? out : ybuf;

    convw_kernel<<<dim3(WN / 4 / 256), dim3(256), 0, stream>>>(W + WN * i, Wbuf);
    ln_kernel<<<dim3(NBATCH), dim3(256), 0, stream>>>(xin, ln_g + (size_t)i * NNODES,
                                                      ln_b + (size_t)i * NNODES, lnbuf);
    gemm256_kernel<<<dim3(256), dim3(512), 0, stream>>>(lnbuf, Wbuf,
                                                        b + (size_t)i * NNODES,
                                                        slope + (size_t)i * NNODES, ydst);
  }
}